// Round 8
// baseline (541.892 us; speedup 1.0000x reference)
//
#include <hip/hip_runtime.h>
#include <hip/hip_bf16.h>
#include <stdint.h>

#define V 32000
#define E 256
#define H 256
#define KCTX 3
#define S 2048
#define B 4
#define M (S * B)      // 8192 rows
#define K1 (KCTX * E)  // 768

typedef __attribute__((ext_vector_type(8))) short s16x8;
typedef __attribute__((ext_vector_type(4))) short s16x4;
typedef __attribute__((ext_vector_type(4))) float f32x4;

static __device__ __forceinline__ unsigned short f2bf(float f) {
  union { float f; unsigned u; } v; v.f = f;
  unsigned u = v.u;
  unsigned r = (u + 0x7fffu + ((u >> 16) & 1u)) >> 16;  // RNE
  return (unsigned short)r;
}

// ---------------------------------------------------------------------------
// Transpose + cast: in (R x C) f32  ->  out (C x R) bf16.  R%32==0, C%32==0.
// ---------------------------------------------------------------------------
__global__ void k_transpose_cast(const float* __restrict__ in,
                                 unsigned short* __restrict__ out,
                                 int R, int C) {
  __shared__ float tile[32][33];
  int bx = blockIdx.x;               // column-tile
  int by = blockIdx.y;               // row-tile
  int tx = threadIdx.x & 31;
  int ty = threadIdx.x >> 5;         // 0..7
#pragma unroll
  for (int i = 0; i < 32; i += 8)
    tile[ty + i][tx] = in[(size_t)(by * 32 + ty + i) * C + bx * 32 + tx];
  __syncthreads();
#pragma unroll
  for (int i = 0; i < 32; i += 8)
    out[(size_t)(bx * 32 + ty + i) * R + by * 32 + tx] = f2bf(tile[tx][ty + i]);
}

// ---------------------------------------------------------------------------
// Stage 1: h = silu(x @ w1 + b1), h bf16 (8192 x 256).
// Block = 4 waves = one 16-row M-tile; x-tile gathered once into LDS.
// ---------------------------------------------------------------------------
__global__ __launch_bounds__(256) void k_stage1(
    const int* __restrict__ tok, const float* __restrict__ embed,
    const unsigned short* __restrict__ w1T,  // (H x K1) bf16, w1T[n][k]
    const float* __restrict__ b1, unsigned short* __restrict__ hbuf) {
  __shared__ unsigned short xlds[16][K1 + 8];
  __shared__ int toks[48];
  int bid = blockIdx.x;        // 0..511
  int t = threadIdx.x;
  int m0 = bid * 16;

  if (t < 48) {
    int r = t / 3, kk = t - r * 3;
    int m = m0 + r, s = m >> 2, bb = m & 3;
    int tp = s - KCTX + kk;
    toks[t] = (tp >= 0) ? tok[tp * B + bb] : 0;
  }
  __syncthreads();

#pragma unroll
  for (int j = 0; j < 12; j++) {
    int c = j * 256 + t;
    int r = c / 192;           // 192 float4 per x-row
    int cc = c - r * 192;      // 0..191
    int kk = cc >> 6;
    int e4 = cc & 63;
    f32x4 v = *reinterpret_cast<const f32x4*>(
        embed + (size_t)toks[r * 3 + kk] * E + e4 * 4);
    s16x4 o;
#pragma unroll
    for (int jj = 0; jj < 4; jj++) o[jj] = (short)f2bf(v[jj]);
    *reinterpret_cast<s16x4*>(&xlds[r][cc * 4]) = o;
  }
  __syncthreads();

  int l = t & 63;
  int wv = t >> 6;
  int n0 = wv * 64;

  f32x4 zero = {0.f, 0.f, 0.f, 0.f};
  f32x4 acc[4];
#pragma unroll
  for (int ni = 0; ni < 4; ni++) acc[ni] = zero;

#pragma unroll
  for (int kt = 0; kt < 24; kt++) {
    s16x8 a = *reinterpret_cast<const s16x8*>(&xlds[l & 15][kt * 32 + (l >> 4) * 8]);
#pragma unroll
    for (int ni = 0; ni < 4; ni++) {
      int n = n0 + ni * 16 + (l & 15);
      s16x8 bf = *reinterpret_cast<const s16x8*>(
          w1T + (size_t)n * K1 + kt * 32 + (l >> 4) * 8);
      acc[ni] = __builtin_amdgcn_mfma_f32_16x16x32_bf16(a, bf, acc[ni], 0, 0, 0);
    }
  }

  int rbase = m0 + (l >> 4) * 4;
#pragma unroll
  for (int ni = 0; ni < 4; ni++) {
    int n = n0 + ni * 16 + (l & 15);
    float bias = b1[n];
#pragma unroll
    for (int j = 0; j < 4; j++) {
      float vv = acc[ni][j] + bias;
      float sv = vv / (1.0f + __expf(-vv));
      hbuf[(size_t)(rbase + j) * H + n] = f2bf(sv);
    }
  }
}

// ---------------------------------------------------------------------------
// Stage 2: out = h @ w2 + b2  (8192 x 32000, K=256).
// NO LDS, NO BARRIERS: operands are cache-resident (A-slice 64 KB in L2 via
// XCD pinning; w2T 16 MB in L3, kept clean by nt-stores), and the MFMA
// fragment is 8 contiguous k per lane = one 16B VMEM load. Each wave loads
// fragments straight to registers; the compiler pipelines VMEM freely since
// there are no sync points — this removes the 2-phase stage/drain serialization
// that made compute and memory add instead of overlap (R7: 316 ≈ 155+180).
// 256-thread blocks (2x2 waves, 128x128 tile), 4 blocks/CU so one block's
// nt-write epilogue overlaps neighbors' K-loops.
// Mapping: 16000 = 8 XCD x 8 mtiles x 250 ntiles (ntile-fastest, bijective).
// ---------------------------------------------------------------------------
__global__ __launch_bounds__(256, 4) void k_stage2(
    const unsigned short* __restrict__ hbuf,  // (8192 x 256) bf16
    const unsigned short* __restrict__ w2T,   // (32000 x 256) bf16
    const float* __restrict__ b2, float* __restrict__ out) {
  int bid = blockIdx.x;
  int xcd = bid & 7;               // dispatch round-robins XCDs
  int i = bid >> 3;                // 0..1999 within XCD
  int mtile = xcd * 8 + i / 250;   // 0..63: 8 mtiles pinned per XCD
  int ntile = i % 250;             // ntile-fastest: A-slice stays L2-hot
  int m_base = mtile * 128, n_base = ntile * 128;

  int t = threadIdx.x;
  int l = t & 63;
  int wv = t >> 6;                // 0..3
  int wm = wv >> 1, wn = wv & 1;  // 2x2 wave grid; wave computes 64x64

  int lr = l & 15;                // fragment row (A) / col (B)
  int lk = (l >> 4) * 8;          // fragment k-offset (8 contiguous bf16)

  f32x4 zero = {0.f, 0.f, 0.f, 0.f};
  f32x4 acc[4][4];
#pragma unroll
  for (int mi = 0; mi < 4; mi++)
#pragma unroll
    for (int ni = 0; ni < 4; ni++) acc[mi][ni] = zero;

  const unsigned short* aptr =
      hbuf + (size_t)(m_base + wm * 64 + lr) * 256 + lk;
  const unsigned short* bptr =
      w2T + (size_t)(n_base + wn * 64 + lr) * 256 + lk;

#pragma unroll
  for (int kt = 0; kt < 8; kt++) {   // K = 8 x 32
    s16x8 af[4], bf[4];
#pragma unroll
    for (int mi = 0; mi < 4; mi++)
      af[mi] = *reinterpret_cast<const s16x8*>(aptr + mi * 16 * 256 + kt * 32);
#pragma unroll
    for (int ni = 0; ni < 4; ni++)
      bf[ni] = *reinterpret_cast<const s16x8*>(bptr + ni * 16 * 256 + kt * 32);
#pragma unroll
    for (int mi = 0; mi < 4; mi++)
#pragma unroll
      for (int ni = 0; ni < 4; ni++)
        acc[mi][ni] = __builtin_amdgcn_mfma_f32_16x16x32_bf16(
            af[mi], bf[ni], acc[mi][ni], 0, 0, 0);
  }

  // epilogue: + b2, NON-TEMPORAL f32 store (keep L2/L3 clean for operands)
#pragma unroll
  for (int ni = 0; ni < 4; ni++) {
    int col = n_base + wn * 64 + ni * 16 + (l & 15);
    float bias = b2[col];
#pragma unroll
    for (int mi = 0; mi < 4; mi++) {
      int row0 = m_base + wm * 64 + mi * 16 + ((l >> 4) * 4);
#pragma unroll
      for (int j = 0; j < 4; j++) {
        float v = acc[mi][ni][j] + bias;
        __builtin_nontemporal_store(v, &out[(size_t)(row0 + j) * V + col]);
      }
    }
  }
}

// ---------------------------------------------------------------------------
extern "C" void kernel_launch(void* const* d_in, const int* in_sizes, int n_in,
                              void* d_out, int out_size, void* d_ws,
                              size_t ws_size, hipStream_t stream) {
  const int* tokens = (const int*)d_in[0];     // (S, B)
  const float* embed = (const float*)d_in[1];  // (V, E)
  const float* w1 = (const float*)d_in[2];     // (K1, H)
  const float* b1 = (const float*)d_in[3];     // (H)
  const float* w2 = (const float*)d_in[4];     // (H, V)
  const float* b2 = (const float*)d_in[5];     // (V)
  float* out = (float*)d_out;

  unsigned short* w2T = (unsigned short*)d_ws;          // V*E   bf16
  unsigned short* w1T = w2T + (size_t)V * E;            // H*K1  bf16
  unsigned short* hb  = w1T + (size_t)H * K1;           // M*H   bf16

  k_transpose_cast<<<dim3(V / 32, H / 32), 256, 0, stream>>>(w2, w2T, H, V);
  k_transpose_cast<<<dim3(H / 32, K1 / 32), 256, 0, stream>>>(w1, w1T, K1, H);
  k_stage1<<<512, 256, 0, stream>>>(tokens, embed, w1T, b1, hb);
  k_stage2<<<16000, 256, 0, stream>>>(hb, w2T, b2, out);
}

// Round 11
// 292.297 us; speedup vs baseline: 1.8539x; 1.8539x over previous
//
#include <hip/hip_runtime.h>
#include <hip/hip_bf16.h>
#include <stdint.h>

#define V 32000
#define E 256
#define H 256
#define KCTX 3
#define S 2048
#define B 4
#define M (S * B)      // 8192 rows
#define K1 (KCTX * E)  // 768

typedef __attribute__((ext_vector_type(8))) short s16x8;
typedef __attribute__((ext_vector_type(4))) short s16x4;
typedef __attribute__((ext_vector_type(4))) float f32x4;

typedef const __attribute__((address_space(1))) unsigned short* gas_t;
typedef __attribute__((address_space(3))) unsigned short* las_t;

static __device__ __forceinline__ unsigned short f2bf(float f) {
  union { float f; unsigned u; } v; v.f = f;
  unsigned u = v.u;
  unsigned r = (u + 0x7fffu + ((u >> 16) & 1u)) >> 16;  // RNE
  return (unsigned short)r;
}

// ---------------------------------------------------------------------------
// Transpose + cast: in (R x C) f32  ->  out (C x R) bf16.  R%32==0, C%32==0.
// ---------------------------------------------------------------------------
__global__ void k_transpose_cast(const float* __restrict__ in,
                                 unsigned short* __restrict__ out,
                                 int R, int C) {
  __shared__ float tile[32][33];
  int bx = blockIdx.x;               // column-tile
  int by = blockIdx.y;               // row-tile
  int tx = threadIdx.x & 31;
  int ty = threadIdx.x >> 5;         // 0..7
#pragma unroll
  for (int i = 0; i < 32; i += 8)
    tile[ty + i][tx] = in[(size_t)(by * 32 + ty + i) * C + bx * 32 + tx];
  __syncthreads();
#pragma unroll
  for (int i = 0; i < 32; i += 8)
    out[(size_t)(bx * 32 + ty + i) * R + by * 32 + tx] = f2bf(tile[tx][ty + i]);
}

// ---------------------------------------------------------------------------
// Stage 1: h = silu(x @ w1 + b1), h bf16 (8192 x 256).
// Block = 4 waves = one 16-row M-tile; x-tile gathered once into LDS.
// ---------------------------------------------------------------------------
__global__ __launch_bounds__(256) void k_stage1(
    const int* __restrict__ tok, const float* __restrict__ embed,
    const unsigned short* __restrict__ w1T,  // (H x K1) bf16, w1T[n][k]
    const float* __restrict__ b1, unsigned short* __restrict__ hbuf) {
  __shared__ unsigned short xlds[16][K1 + 8];
  __shared__ int toks[48];
  int bid = blockIdx.x;        // 0..511
  int t = threadIdx.x;
  int m0 = bid * 16;

  if (t < 48) {
    int r = t / 3, kk = t - r * 3;
    int m = m0 + r, s = m >> 2, bb = m & 3;
    int tp = s - KCTX + kk;
    toks[t] = (tp >= 0) ? tok[tp * B + bb] : 0;
  }
  __syncthreads();

#pragma unroll
  for (int j = 0; j < 12; j++) {
    int c = j * 256 + t;
    int r = c / 192;           // 192 float4 per x-row
    int cc = c - r * 192;      // 0..191
    int kk = cc >> 6;
    int e4 = cc & 63;
    f32x4 v = *reinterpret_cast<const f32x4*>(
        embed + (size_t)toks[r * 3 + kk] * E + e4 * 4);
    s16x4 o;
#pragma unroll
    for (int jj = 0; jj < 4; jj++) o[jj] = (short)f2bf(v[jj]);
    *reinterpret_cast<s16x4*>(&xlds[r][cc * 4]) = o;
  }
  __syncthreads();

  int l = t & 63;
  int wv = t >> 6;
  int n0 = wv * 64;

  f32x4 zero = {0.f, 0.f, 0.f, 0.f};
  f32x4 acc[4];
#pragma unroll
  for (int ni = 0; ni < 4; ni++) acc[ni] = zero;

#pragma unroll
  for (int kt = 0; kt < 24; kt++) {
    s16x8 a = *reinterpret_cast<const s16x8*>(&xlds[l & 15][kt * 32 + (l >> 4) * 8]);
#pragma unroll
    for (int ni = 0; ni < 4; ni++) {
      int n = n0 + ni * 16 + (l & 15);
      s16x8 bf = *reinterpret_cast<const s16x8*>(
          w1T + (size_t)n * K1 + kt * 32 + (l >> 4) * 8);
      acc[ni] = __builtin_amdgcn_mfma_f32_16x16x32_bf16(a, bf, acc[ni], 0, 0, 0);
    }
  }

  int rbase = m0 + (l >> 4) * 4;
#pragma unroll
  for (int ni = 0; ni < 4; ni++) {
    int n = n0 + ni * 16 + (l & 15);
    float bias = b1[n];
#pragma unroll
    for (int j = 0; j < 4; j++) {
      float vv = acc[ni][j] + bias;
      float sv = vv / (1.0f + __expf(-vv));
      hbuf[(size_t)(rbase + j) * H + n] = f2bf(sv);
    }
  }
}

// ---------------------------------------------------------------------------
// Stage 2: out = h @ w2 + b2  (8192 x 32000, K=256).
// K-loop/staging byte-identical to round-7 (351 us, passing). ONE change:
// the epilogue bounces acc through a wave-private LDS patch ([16][68] f32,
// reusing the staging LDS after the K-loop's final barrier) and stores
// 256B-CONTIGUOUS row segments (16 lanes x 16B per row) instead of 4B/lane
// at 128KB row stride. Old pattern = 64B segments = half of every 128B line
// per transaction -> ~2x write cost (R7: stage2 ~316us ~= 2x the 155us
// write floor). Full-line nt stores should run at fill-kernel efficiency.
// ---------------------------------------------------------------------------
__global__ __launch_bounds__(512, 4) void k_stage2(
    const unsigned short* __restrict__ hbuf,  // (8192 x 256) bf16
    const unsigned short* __restrict__ w2T,   // (32000 x 256) bf16
    const float* __restrict__ b2, float* __restrict__ out) {
  __shared__ unsigned short lds[2][12288];  // per buf: A 256x32 (8192) + B 128x32 (4096)

  int bid = blockIdx.x;
  int xcd = bid & 7;          // dispatch round-robins XCDs
  int i = bid >> 3;           // 0..999 within XCD
  int mtile = xcd * 4 + i / 250;  // 0..31: 4 mtiles pinned per XCD
  int ntile = i % 250;            // ntile-fastest: A-slice L2-resident
  int m_base = mtile * 256, n_base = ntile * 128;

  int t = threadIdx.x;
  int l = t & 63;
  int wv = t >> 6;                // 0..7
  int wm = wv >> 1, wn = wv & 1;  // 4x2 wave grid; wave computes 64x64

  int srow = l >> 2;   // lane's row within a 16-row staging call (64B rows)
  int c4 = l & 3;      // lane's 16B chunk within a 64B row

  f32x4 zero = {0.f, 0.f, 0.f, 0.f};
  f32x4 acc[4][4];
#pragma unroll
  for (int mi = 0; mi < 4; mi++)
#pragma unroll
    for (int ni = 0; ni < 4; ni++) acc[mi][ni] = zero;

  // stage K-slice tt (BK=32) into buffer p: 3 gload_lds per wave.
  // Global source chunk is XOR-permuted so linear LDS dest leaves data at
  // chunk (c ^ ((row>>1)&3))  [rule 21: swizzle both sides or neither].
  auto stage = [&](int tt, int p) {
    int gk = tt * 32;
#pragma unroll
    for (int j = 0; j < 2; j++) {          // A: 256 rows
      int r0 = wv * 32 + j * 16;
      int row = r0 + srow;
      int gc = c4 ^ ((row >> 1) & 3);
      const unsigned short* ga =
          hbuf + (size_t)(m_base + row) * 256 + gk + gc * 8;
      __builtin_amdgcn_global_load_lds((gas_t)ga, (las_t)&lds[p][r0 * 32], 16, 0, 0);
    }
    {                                      // B: 128 rows
      int r0 = wv * 16;
      int row = r0 + srow;
      int gc = c4 ^ ((row >> 1) & 3);
      const unsigned short* gb =
          w2T + (size_t)(n_base + row) * 256 + gk + gc * 8;
      __builtin_amdgcn_global_load_lds((gas_t)gb, (las_t)&lds[p][8192 + r0 * 32], 16, 0, 0);
    }
  };

  auto compute = [&](int p) {
    const unsigned short* bufA = &lds[p][0];
    const unsigned short* bufB = &lds[p][8192];
    int c = l >> 4;  // lane's K-chunk (0..3)
    s16x8 af[4], bfr[4];
#pragma unroll
    for (int mi = 0; mi < 4; mi++) {
      int row = wm * 64 + mi * 16 + (l & 15);
      af[mi] = *reinterpret_cast<const s16x8*>(
          bufA + row * 32 + (c ^ ((row >> 1) & 3)) * 8);
    }
#pragma unroll
    for (int ni = 0; ni < 4; ni++) {
      int row = wn * 64 + ni * 16 + (l & 15);
      bfr[ni] = *reinterpret_cast<const s16x8*>(
          bufB + row * 32 + (c ^ ((row >> 1) & 3)) * 8);
    }
#pragma unroll
    for (int mi = 0; mi < 4; mi++)
#pragma unroll
      for (int ni = 0; ni < 4; ni++)
        acc[mi][ni] = __builtin_amdgcn_mfma_f32_16x16x32_bf16(
            af[mi], bfr[ni], acc[mi][ni], 0, 0, 0);
  };

  stage(0, 0);
  __syncthreads();
#pragma unroll
  for (int tt = 0; tt < 8; tt++) {
    if (tt < 7) stage(tt + 1, (tt + 1) & 1);  // prefetch: flies during compute
    compute(tt & 1);
    __syncthreads();  // full fence: loads landed + all reads of buf done
  }
  // K-loop done; final barrier passed -> staging LDS is free for reuse.

  // epilogue: + b2, bounce through wave-private LDS patch, then nt-store
  // 256B-contiguous row segments (full 128B lines per transaction).
  float* fpatch = reinterpret_cast<float*>(&lds[0][0]) + wv * 1088;  // [16][68]
  int q = l >> 4, r = l & 15;
  float bias[4];
#pragma unroll
  for (int ni = 0; ni < 4; ni++)
    bias[ni] = b2[n_base + wn * 64 + ni * 16 + r];

#pragma unroll
  for (int mi = 0; mi < 4; mi++) {
    // scatter acc[mi] (+bias) into patch: row q*4+j, col ni*16+r  (2-way: free)
#pragma unroll
    for (int ni = 0; ni < 4; ni++)
#pragma unroll
      for (int j = 0; j < 4; j++)
        fpatch[(q * 4 + j) * 68 + ni * 16 + r] = acc[mi][ni][j] + bias[ni];
    // read back row-major (wave-private: no barrier; lgkmcnt by compiler)
#pragma unroll
    for (int it = 0; it < 4; it++) {
      int row16 = it * 4 + q;     // 4 rows per instr, 16 lanes per row
      f32x4 v = *reinterpret_cast<const f32x4*>(fpatch + row16 * 68 + r * 4);
      float* dst = &out[(size_t)(m_base + wm * 64 + mi * 16 + row16) * V +
                        n_base + wn * 64 + r * 4];
      __builtin_nontemporal_store(v, reinterpret_cast<f32x4*>(dst));
    }
    // next mi overwrites the patch: same-wave DS ops are in-order -> safe
  }
}

// ---------------------------------------------------------------------------
extern "C" void kernel_launch(void* const* d_in, const int* in_sizes, int n_in,
                              void* d_out, int out_size, void* d_ws,
                              size_t ws_size, hipStream_t stream) {
  const int* tokens = (const int*)d_in[0];     // (S, B)
  const float* embed = (const float*)d_in[1];  // (V, E)
  const float* w1 = (const float*)d_in[2];     // (K1, H)
  const float* b1 = (const float*)d_in[3];     // (H)
  const float* w2 = (const float*)d_in[4];     // (H, V)
  const float* b2 = (const float*)d_in[5];     // (V)
  float* out = (float*)d_out;

  unsigned short* w2T = (unsigned short*)d_ws;          // V*E   bf16
  unsigned short* w1T = w2T + (size_t)V * E;            // H*K1  bf16
  unsigned short* hb  = w1T + (size_t)H * K1;           // M*H   bf16

  k_transpose_cast<<<dim3(V / 32, H / 32), 256, 0, stream>>>(w2, w2T, H, V);
  k_transpose_cast<<<dim3(H / 32, K1 / 32), 256, 0, stream>>>(w1, w1T, K1, H);
  k_stage1<<<512, 256, 0, stream>>>(tokens, embed, w1T, b1, hb);
  k_stage2<<<8000, 512, 0, stream>>>(hb, w2T, b2, out);
}

// Round 12
// 270.916 us; speedup vs baseline: 2.0002x; 1.0789x over previous
//
#include <hip/hip_runtime.h>
#include <hip/hip_bf16.h>
#include <stdint.h>

#define V 32000
#define E 256
#define H 256
#define KCTX 3
#define S 2048
#define B 4
#define M (S * B)      // 8192 rows
#define K1 (KCTX * E)  // 768

typedef __attribute__((ext_vector_type(8))) short s16x8;
typedef __attribute__((ext_vector_type(4))) short s16x4;
typedef __attribute__((ext_vector_type(4))) float f32x4;

typedef const __attribute__((address_space(1))) unsigned short* gas_t;
typedef __attribute__((address_space(3))) unsigned short* las_t;

static __device__ __forceinline__ unsigned short f2bf(float f) {
  union { float f; unsigned u; } v; v.f = f;
  unsigned u = v.u;
  unsigned r = (u + 0x7fffu + ((u >> 16) & 1u)) >> 16;  // RNE
  return (unsigned short)r;
}

// ---------------------------------------------------------------------------
// Transpose + cast: in (R x C) f32  ->  out (C x R) bf16.  R%32==0, C%32==0.
// ---------------------------------------------------------------------------
__global__ void k_transpose_cast(const float* __restrict__ in,
                                 unsigned short* __restrict__ out,
                                 int R, int C) {
  __shared__ float tile[32][33];
  int bx = blockIdx.x;               // column-tile
  int by = blockIdx.y;               // row-tile
  int tx = threadIdx.x & 31;
  int ty = threadIdx.x >> 5;         // 0..7
#pragma unroll
  for (int i = 0; i < 32; i += 8)
    tile[ty + i][tx] = in[(size_t)(by * 32 + ty + i) * C + bx * 32 + tx];
  __syncthreads();
#pragma unroll
  for (int i = 0; i < 32; i += 8)
    out[(size_t)(bx * 32 + ty + i) * R + by * 32 + tx] = f2bf(tile[tx][ty + i]);
}

// ---------------------------------------------------------------------------
// Stage 1: h = silu(x @ w1 + b1), h bf16 (8192 x 256).
// Block = 4 waves = one 16-row M-tile; x-tile gathered once into LDS.
// ---------------------------------------------------------------------------
__global__ __launch_bounds__(256) void k_stage1(
    const int* __restrict__ tok, const float* __restrict__ embed,
    const unsigned short* __restrict__ w1T,  // (H x K1) bf16, w1T[n][k]
    const float* __restrict__ b1, unsigned short* __restrict__ hbuf) {
  __shared__ unsigned short xlds[16][K1 + 8];
  __shared__ int toks[48];
  int bid = blockIdx.x;        // 0..511
  int t = threadIdx.x;
  int m0 = bid * 16;

  if (t < 48) {
    int r = t / 3, kk = t - r * 3;
    int m = m0 + r, s = m >> 2, bb = m & 3;
    int tp = s - KCTX + kk;
    toks[t] = (tp >= 0) ? tok[tp * B + bb] : 0;
  }
  __syncthreads();

#pragma unroll
  for (int j = 0; j < 12; j++) {
    int c = j * 256 + t;
    int r = c / 192;           // 192 float4 per x-row
    int cc = c - r * 192;      // 0..191
    int kk = cc >> 6;
    int e4 = cc & 63;
    f32x4 v = *reinterpret_cast<const f32x4*>(
        embed + (size_t)toks[r * 3 + kk] * E + e4 * 4);
    s16x4 o;
#pragma unroll
    for (int jj = 0; jj < 4; jj++) o[jj] = (short)f2bf(v[jj]);
    *reinterpret_cast<s16x4*>(&xlds[r][cc * 4]) = o;
  }
  __syncthreads();

  int l = t & 63;
  int wv = t >> 6;
  int n0 = wv * 64;

  f32x4 zero = {0.f, 0.f, 0.f, 0.f};
  f32x4 acc[4];
#pragma unroll
  for (int ni = 0; ni < 4; ni++) acc[ni] = zero;

#pragma unroll
  for (int kt = 0; kt < 24; kt++) {
    s16x8 a = *reinterpret_cast<const s16x8*>(&xlds[l & 15][kt * 32 + (l >> 4) * 8]);
#pragma unroll
    for (int ni = 0; ni < 4; ni++) {
      int n = n0 + ni * 16 + (l & 15);
      s16x8 bf = *reinterpret_cast<const s16x8*>(
          w1T + (size_t)n * K1 + kt * 32 + (l >> 4) * 8);
      acc[ni] = __builtin_amdgcn_mfma_f32_16x16x32_bf16(a, bf, acc[ni], 0, 0, 0);
    }
  }

  int rbase = m0 + (l >> 4) * 4;
#pragma unroll
  for (int ni = 0; ni < 4; ni++) {
    int n = n0 + ni * 16 + (l & 15);
    float bias = b1[n];
#pragma unroll
    for (int j = 0; j < 4; j++) {
      float vv = acc[ni][j] + bias;
      float sv = vv / (1.0f + __expf(-vv));
      hbuf[(size_t)(rbase + j) * H + n] = f2bf(sv);
    }
  }
}

// ---------------------------------------------------------------------------
// Stage 2: out = h @ w2 + b2  (8192 x 32000, K=256).
// vs round-11 (292 us): TWO changes.
// 1. RACE FIX: __syncthreads() between the K-loop and the LDS-bounce
//    epilogue (waves 5-7's fpatch overflows into lds[1], which other waves
//    were still reading in compute(7) — passed by lockstep luck only).
// 2. B-REUSE ordering: within each XCD, mtile_local = i&3, ntile = i>>2.
//    4 consecutive (concurrent) blocks share one B-tile (L2-hit) and the 4
//    A-slices (256 KB) stay L2-resident. Per-XCD B traffic 64 MB -> 16 MB;
//    chip-wide L3 reads 512 MB -> 128 MB, which was ~90 us of memory-system
//    contention with the 157-us write stream.
// Everything else byte-identical (nt-stores kept).
// ---------------------------------------------------------------------------
__global__ __launch_bounds__(512, 4) void k_stage2(
    const unsigned short* __restrict__ hbuf,  // (8192 x 256) bf16
    const unsigned short* __restrict__ w2T,   // (32000 x 256) bf16
    const float* __restrict__ b2, float* __restrict__ out) {
  __shared__ unsigned short lds[2][12288];  // per buf: A 256x32 (8192) + B 128x32 (4096)

  int bid = blockIdx.x;
  int xcd = bid & 7;               // dispatch round-robins XCDs
  int i = bid >> 3;                // 0..999 within XCD
  int mtile = xcd * 4 + (i & 3);   // 4 mtiles per XCD, cycled fastest
  int ntile = i >> 2;              // 250 ntiles; B-tile shared by 4 blocks
  int m_base = mtile * 256, n_base = ntile * 128;

  int t = threadIdx.x;
  int l = t & 63;
  int wv = t >> 6;                // 0..7
  int wm = wv >> 1, wn = wv & 1;  // 4x2 wave grid; wave computes 64x64

  int srow = l >> 2;   // lane's row within a 16-row staging call (64B rows)
  int c4 = l & 3;      // lane's 16B chunk within a 64B row

  f32x4 zero = {0.f, 0.f, 0.f, 0.f};
  f32x4 acc[4][4];
#pragma unroll
  for (int mi = 0; mi < 4; mi++)
#pragma unroll
    for (int ni = 0; ni < 4; ni++) acc[mi][ni] = zero;

  // stage K-slice tt (BK=32) into buffer p: 3 gload_lds per wave.
  // Global source chunk is XOR-permuted so linear LDS dest leaves data at
  // chunk (c ^ ((row>>1)&3))  [rule 21: swizzle both sides or neither].
  auto stage = [&](int tt, int p) {
    int gk = tt * 32;
#pragma unroll
    for (int j = 0; j < 2; j++) {          // A: 256 rows
      int r0 = wv * 32 + j * 16;
      int row = r0 + srow;
      int gc = c4 ^ ((row >> 1) & 3);
      const unsigned short* ga =
          hbuf + (size_t)(m_base + row) * 256 + gk + gc * 8;
      __builtin_amdgcn_global_load_lds((gas_t)ga, (las_t)&lds[p][r0 * 32], 16, 0, 0);
    }
    {                                      // B: 128 rows
      int r0 = wv * 16;
      int row = r0 + srow;
      int gc = c4 ^ ((row >> 1) & 3);
      const unsigned short* gb =
          w2T + (size_t)(n_base + row) * 256 + gk + gc * 8;
      __builtin_amdgcn_global_load_lds((gas_t)gb, (las_t)&lds[p][8192 + r0 * 32], 16, 0, 0);
    }
  };

  auto compute = [&](int p) {
    const unsigned short* bufA = &lds[p][0];
    const unsigned short* bufB = &lds[p][8192];
    int c = l >> 4;  // lane's K-chunk (0..3)
    s16x8 af[4], bfr[4];
#pragma unroll
    for (int mi = 0; mi < 4; mi++) {
      int row = wm * 64 + mi * 16 + (l & 15);
      af[mi] = *reinterpret_cast<const s16x8*>(
          bufA + row * 32 + (c ^ ((row >> 1) & 3)) * 8);
    }
#pragma unroll
    for (int ni = 0; ni < 4; ni++) {
      int row = wn * 64 + ni * 16 + (l & 15);
      bfr[ni] = *reinterpret_cast<const s16x8*>(
          bufB + row * 32 + (c ^ ((row >> 1) & 3)) * 8);
    }
#pragma unroll
    for (int mi = 0; mi < 4; mi++)
#pragma unroll
      for (int ni = 0; ni < 4; ni++)
        acc[mi][ni] = __builtin_amdgcn_mfma_f32_16x16x32_bf16(
            af[mi], bfr[ni], acc[mi][ni], 0, 0, 0);
  };

  stage(0, 0);
  __syncthreads();
#pragma unroll
  for (int tt = 0; tt < 8; tt++) {
    if (tt < 7) stage(tt + 1, (tt + 1) & 1);  // prefetch: flies during compute
    compute(tt & 1);
    __syncthreads();  // full fence: loads landed + all reads of buf done
  }
  __syncthreads();  // RACE FIX: all compute(7) LDS reads done before fpatch
                    // writes (waves 5-7's patches overlap lds[1]'s A region)

  // epilogue: + b2, bounce through wave-private LDS patch, then nt-store
  // 256B-contiguous row segments (full 128B lines per transaction).
  float* fpatch = reinterpret_cast<float*>(&lds[0][0]) + wv * 1088;  // [16][68]
  int q = l >> 4, r = l & 15;
  float bias[4];
#pragma unroll
  for (int ni = 0; ni < 4; ni++)
    bias[ni] = b2[n_base + wn * 64 + ni * 16 + r];

#pragma unroll
  for (int mi = 0; mi < 4; mi++) {
    // scatter acc[mi] (+bias) into patch: row q*4+j, col ni*16+r  (2-way: free)
#pragma unroll
    for (int ni = 0; ni < 4; ni++)
#pragma unroll
      for (int j = 0; j < 4; j++)
        fpatch[(q * 4 + j) * 68 + ni * 16 + r] = acc[mi][ni][j] + bias[ni];
    // read back row-major (wave-private: no barrier; lgkmcnt by compiler)
#pragma unroll
    for (int it = 0; it < 4; it++) {
      int row16 = it * 4 + q;     // 4 rows per instr, 16 lanes per row
      f32x4 v = *reinterpret_cast<const f32x4*>(fpatch + row16 * 68 + r * 4);
      float* dst = &out[(size_t)(m_base + wm * 64 + mi * 16 + row16) * V +
                        n_base + wn * 64 + r * 4];
      __builtin_nontemporal_store(v, reinterpret_cast<f32x4*>(dst));
    }
    // next mi overwrites the patch: same-wave DS ops are in-order -> safe
  }
}

// ---------------------------------------------------------------------------
extern "C" void kernel_launch(void* const* d_in, const int* in_sizes, int n_in,
                              void* d_out, int out_size, void* d_ws,
                              size_t ws_size, hipStream_t stream) {
  const int* tokens = (const int*)d_in[0];     // (S, B)
  const float* embed = (const float*)d_in[1];  // (V, E)
  const float* w1 = (const float*)d_in[2];     // (K1, H)
  const float* b1 = (const float*)d_in[3];     // (H)
  const float* w2 = (const float*)d_in[4];     // (H, V)
  const float* b2 = (const float*)d_in[5];     // (V)
  float* out = (float*)d_out;

  unsigned short* w2T = (unsigned short*)d_ws;          // V*E   bf16
  unsigned short* w1T = w2T + (size_t)V * E;            // H*K1  bf16
  unsigned short* hb  = w1T + (size_t)H * K1;           // M*H   bf16

  k_transpose_cast<<<dim3(V / 32, H / 32), 256, 0, stream>>>(w2, w2T, H, V);
  k_transpose_cast<<<dim3(H / 32, K1 / 32), 256, 0, stream>>>(w1, w1T, K1, H);
  k_stage1<<<512, 256, 0, stream>>>(tokens, embed, w1T, b1, hb);
  k_stage2<<<8000, 512, 0, stream>>>(hb, w2T, b2, out);
}